// Round 4
// baseline (46.513 us; speedup 1.0000x reference)
//
#include <hip/hip_runtime.h>

typedef float f32x16 __attribute__((ext_vector_type(16)));
typedef short bf16x8 __attribute__((ext_vector_type(8)));

#define BLOCK 256
#define NPTS 4096
#define CHUNK_PTS 256                 // points staged per LDS chunk (8KB)
#define NCHUNK (NPTS / CHUNK_PTS)     // 16
#define SUBS (CHUNK_PTS / 32)         // 8 j-tiles (32 pts) per chunk
#define TW 2                          // 32-row tiles per wave
#define TILES_PER_BLOCK 8             // 4 waves * TW

// ---------- bf16 helpers ----------
__device__ inline unsigned int f2bf(float x) {   // RNE float->bf16 bits
    unsigned int u = __float_as_uint(x);
    return (u + 0x7FFFu + ((u >> 16) & 1)) >> 16;
}
__device__ inline float bf2f(unsigned int b) { return __uint_as_float(b << 16); }
__device__ inline unsigned int pk2(unsigned int lo, unsigned int hi) {
    return (hi << 16) | (lo & 0xFFFFu);
}

// Pack each point into two 32B (K=16 bf16) records.
// Slot pairing (kappa): 0..2: A=-2h * B=h' ; 3..5: A=-2l * B=h' ;
// 6..8: A=-2h * B=l' ; 9: A=1 * B=hw' ; 10: A=1 * B=lw' ; 11..15: 0.
// => MFMA acc = q.w - 2*dot(p,q) with error ~1e-4 (dropped l*l' terms).
__global__ __launch_bounds__(BLOCK) void pack_pts(
    const float* __restrict__ x1, const float* __restrict__ x2,
    uint4* __restrict__ arrA, uint4* __restrict__ arrB,
    float* __restrict__ wn, int n1, int ntot, float* __restrict__ out) {
    int i = blockIdx.x * BLOCK + threadIdx.x;
    if (i == 0) out[0] = 0.0f;
    if (i >= ntot) return;
    const float* s = (i < n1) ? x1 + 3 * (size_t)i : x2 + 3 * (size_t)(i - n1);
    float x = s[0], y = s[1], z = s[2];
    float w = fmaf(z, z, fmaf(y, y, x * x));
    wn[i] = w;
    unsigned int hx = f2bf(x), hy = f2bf(y), hz = f2bf(z);
    unsigned int lx = f2bf(x - bf2f(hx)), ly = f2bf(y - bf2f(hy)), lz = f2bf(z - bf2f(hz));
    unsigned int hw = f2bf(w), lw = f2bf(w - bf2f(hw));
    // -2*h, -2*l are exact (power-of-2 scale of a bf16 value)
    unsigned int ax = f2bf(-2.f * bf2f(hx)), ay = f2bf(-2.f * bf2f(hy)), az = f2bf(-2.f * bf2f(hz));
    unsigned int bx = f2bf(-2.f * bf2f(lx)), by = f2bf(-2.f * bf2f(ly)), bz = f2bf(-2.f * bf2f(lz));
    const unsigned int one = 0x3F80u;
    uint4 A0 = make_uint4(pk2(ax, ay), pk2(az, bx), pk2(by, bz), pk2(ax, ay));
    uint4 A1 = make_uint4(pk2(az, one), pk2(one, 0u), 0u, 0u);
    arrA[(size_t)i * 2 + 0] = A0;
    arrA[(size_t)i * 2 + 1] = A1;
    uint4 B0 = make_uint4(pk2(hx, hy), pk2(hz, hx), pk2(hy, hz), pk2(lx, ly));
    uint4 B1 = make_uint4(pk2(lz, hw), pk2(lw, 0u), 0u, 0u);
    arrB[(size_t)i * 2 + 0] = B0;
    arrB[(size_t)i * 2 + 1] = B1;
}

// MFMA min pass. grid = Bc*2*16 blocks; block = (b,dir,row-segment of 256 rows).
// Each of 4 waves owns TW=2 32-row tiles (A-frags in regs); block stages the
// scanned cloud in 8KB LDS chunks; per 32-col sub-tile one ds_read_b128 feeds
// 2 MFMAs; running min folded with min3 over sub pairs. Epilogue: butterfly
// col-min, add p.w (fp32), block-reduce, one atomicAdd per block.
__global__ __launch_bounds__(BLOCK) void chamfer_mfma(
    const uint4* __restrict__ arrA, const uint4* __restrict__ arrB,
    const float* __restrict__ wn, int n1, int Bc,
    float inv1, float inv2, float* __restrict__ out) {
    __shared__ uint4 lds[CHUNK_PTS * 2];   // 8KB
    __shared__ float red[4];
    int tid = threadIdx.x;
    int lane = tid & 63, widx = tid >> 6;
    int l31 = lane & 31, blk = lane >> 5;

    int bid = blockIdx.x;
    int bd = bid >> 4;           // (dir,b)
    int seg = bid & 15;          // row segment (256 rows each)
    int dir = (bd >= Bc) ? 1 : 0;
    int b = dir ? bd - Bc : bd;
    int ownOff = dir ? n1 : 0;
    int othOff = dir ? 0 : n1;
    float inv = dir ? inv2 : inv1;

    int tile0 = seg * TILES_PER_BLOCK + widx * TW;  // of 128 tiles per batch
    int row0 = tile0 * 32;

    size_t aBase = (size_t)(ownOff + b * NPTS + row0 + l31) * 2 + blk;
    bf16x8 afA = *(const bf16x8*)(arrA + aBase);
    bf16x8 afB = *(const bf16x8*)(arrA + aBase + 64);  // +32 points * 2 uint4

    const uint4* gB = arrB + (size_t)(othOff + b * NPTS) * 2;

    f32x16 runA, runB;
#pragma unroll
    for (int r = 0; r < 16; ++r) { runA[r] = 3.0e38f; runB[r] = 3.0e38f; }

    // stage chunk 0
    uint4 p0 = gB[tid], p1 = gB[tid + 256];
    lds[tid] = p0;
    lds[tid + 256] = p1;
    __syncthreads();

    f32x16 zero = {};
    for (int c = 0; c < NCHUNK; ++c) {
        if (c + 1 < NCHUNK) {   // prefetch next chunk into regs (hides L2)
            p0 = gB[(c + 1) * 512 + tid];
            p1 = gB[(c + 1) * 512 + 256 + tid];
        }
        const bf16x8* lp = (const bf16x8*)lds;
#pragma unroll
        for (int s = 0; s < SUBS; s += 2) {
            bf16x8 bf0 = lp[(s * 32 + l31) * 2 + blk];
            bf16x8 bf1 = lp[((s + 1) * 32 + l31) * 2 + blk];
            f32x16 acc0a = __builtin_amdgcn_mfma_f32_32x32x16_bf16(afA, bf0, zero, 0, 0, 0);
            f32x16 acc0b = __builtin_amdgcn_mfma_f32_32x32x16_bf16(afB, bf0, zero, 0, 0, 0);
            f32x16 acc1a = __builtin_amdgcn_mfma_f32_32x32x16_bf16(afA, bf1, zero, 0, 0, 0);
            f32x16 acc1b = __builtin_amdgcn_mfma_f32_32x32x16_bf16(afB, bf1, zero, 0, 0, 0);
#pragma unroll
            for (int r = 0; r < 16; ++r) {   // hope: v_min3_f32
                runA[r] = fminf(runA[r], fminf(acc0a[r], acc1a[r]));
                runB[r] = fminf(runB[r], fminf(acc0b[r], acc1b[r]));
            }
        }
        __syncthreads();
        if (c + 1 < NCHUNK) {
            lds[tid] = p0;
            lds[tid + 256] = p1;
        }
        __syncthreads();
    }

    // butterfly min over the 32 columns (lanes within each half)
#pragma unroll
    for (int m = 1; m <= 16; m <<= 1) {
#pragma unroll
        for (int r = 0; r < 16; ++r) {
            runA[r] = fminf(runA[r], __shfl_xor(runA[r], m, 64));
            runB[r] = fminf(runB[r], __shfl_xor(runB[r], m, 64));
        }
    }
    // C/D layout (verified): col=lane&31, row=(r&3)+8*(r>>2)+4*(lane>>5)
    float contrib = 0.0f;
    if (l31 == 0) {
        const float* wp = wn + ownOff + b * NPTS;
#pragma unroll
        for (int r = 0; r < 16; ++r) {
            int rowA = row0 + ((r & 3) + 8 * (r >> 2) + 4 * blk);
            contrib += runA[r] + wp[rowA];
            contrib += runB[r] + wp[rowA + 32];
        }
    }
    contrib += __shfl_xor(contrib, 32, 64);  // combine the two halves
    if (lane == 0) red[widx] = contrib * inv;
    __syncthreads();
    if (tid == 0) atomicAdd(out, red[0] + red[1] + red[2] + red[3]);
}

// Fallback (no scratch / unexpected shape): direct-diff scalar path.
__global__ __launch_bounds__(BLOCK) void chamfer_direct(
    const float* __restrict__ x1, const float* __restrict__ x2,
    int Npts, int Mpts, float inv1, float inv2, float* __restrict__ out) {
    int dir = blockIdx.z;
    const float* own = dir ? x2 : x1;
    const float* oth = dir ? x1 : x2;
    int np = dir ? Mpts : Npts;
    int mp = dir ? Npts : Mpts;
    float scale = dir ? inv2 : inv1;

    int bpb = np / BLOCK;
    int b = blockIdx.x / bpb;
    int i = (blockIdx.x % bpb) * BLOCK + threadIdx.x;

    const float* pp = own + ((size_t)b * np + i) * 3;
    float px = pp[0], py = pp[1], pz = pp[2];
    const float* o = oth + (size_t)b * mp * 3;

    float best = 3.0e38f;
#pragma unroll 4
    for (int j = 0; j < mp; ++j) {
        float dx = px - o[3 * j + 0];
        float dy = py - o[3 * j + 1];
        float dz = pz - o[3 * j + 2];
        float d2 = fmaf(dz, dz, fmaf(dy, dy, dx * dx));
        best = fminf(best, d2);
    }
    float s = best * scale;
    for (int off = 32; off; off >>= 1) s += __shfl_down(s, off, 64);
    __shared__ float red[BLOCK / 64];
    int lane = threadIdx.x & 63, wid = threadIdx.x >> 6;
    if (!lane) red[wid] = s;
    __syncthreads();
    if (!threadIdx.x) atomicAdd(out, red[0] + red[1] + red[2] + red[3]);
}

extern "C" void kernel_launch(void* const* d_in, const int* in_sizes, int n_in,
                              void* d_out, int out_size, void* d_ws, size_t ws_size,
                              hipStream_t stream) {
    const float* xyz1 = (const float*)d_in[0];
    const float* xyz2 = (const float*)d_in[1];
    float* out = (float*)d_out;

    const int Bc = in_sizes[0] / (3 * NPTS);
    const int n1 = Bc * NPTS;
    const int n2 = Bc * NPTS;
    const int ntot = n1 + n2;

    size_t need = (size_t)ntot * (32 + 32 + 4);  // arrA + arrB + wn
    bool okShape = Bc >= 1 && in_sizes[0] == Bc * 3 * NPTS && in_sizes[1] == in_sizes[0];

    if (okShape && ws_size >= need) {
        uint4* arrA = (uint4*)d_ws;
        uint4* arrB = (uint4*)((char*)d_ws + (size_t)ntot * 32);
        float* wn = (float*)((char*)d_ws + (size_t)ntot * 64);

        pack_pts<<<(ntot + BLOCK - 1) / BLOCK, BLOCK, 0, stream>>>(
            xyz1, xyz2, arrA, arrB, wn, n1, ntot, out);

        chamfer_mfma<<<Bc * 2 * 16, BLOCK, 0, stream>>>(
            arrA, arrB, wn, n1, Bc,
            1.0f / (float)n1, 1.0f / (float)n2, out);
    } else {
        hipMemsetAsync(d_out, 0, sizeof(float), stream);
        dim3 grid((in_sizes[0] / 3 / NPTS) * (NPTS / BLOCK), 1, 2);
        chamfer_direct<<<grid, BLOCK, 0, stream>>>(xyz1, xyz2, NPTS, NPTS,
                                                   1.0f / (float)n1, 1.0f / (float)n2, out);
    }
}

// Round 5
// 39.481 us; speedup vs baseline: 1.1781x; 1.1781x over previous
//
#include <hip/hip_runtime.h>

typedef float f32x16 __attribute__((ext_vector_type(16)));
typedef short bf16x8 __attribute__((ext_vector_type(8)));

#define BLOCK 256
#define NPTS 4096
#define SEGS 32                      // row segments per (b,dir): 128 rows each
#define SCANSPLIT 2                  // scan halves per (b,dir)
#define SCANPTS (NPTS / SCANSPLIT)   // 2048
#define CHUNK 256                    // scanned points per LDS chunk
#define NCHUNK (SCANPTS / CHUNK)     // 8
#define SUBS (CHUNK / 32)            // 8 col-subtiles per chunk

// ---------- bf16 helpers ----------
__device__ inline unsigned int f2bf(float x) {   // RNE float->bf16 bits
    unsigned int u = __float_as_uint(x);
    return (u + 0x7FFFu + ((u >> 16) & 1)) >> 16;
}
__device__ inline float bf2f(unsigned int b) { return __uint_as_float(b << 16); }
__device__ inline unsigned int pk2(unsigned int lo, unsigned int hi) {
    return (hi << 16) | (lo & 0xFFFFu);
}
// order-preserving float->uint key (works for negatives), and inverse
__device__ inline unsigned int fkey(float f) {
    unsigned int u = __float_as_uint(f);
    return (u & 0x80000000u) ? ~u : (u | 0x80000000u);
}
__device__ inline float funkey(unsigned int k) {
    unsigned int u = (k & 0x80000000u) ? (k & 0x7FFFFFFFu) : ~k;
    return __uint_as_float(u);
}

// Pack each point into two 32B (K=16 bf16) records (verified: absmax 0.0).
// kappa slots: 0..2: A=-2h * B=h' ; 3..5: A=-2l * B=h' ; 6..8: A=-2h * B=l' ;
// 9: A=1 * B=hw' ; 10: A=1 * B=lw' ; 11..15: 0.
// => MFMA acc = q.w - 2*dot(p,q).
__global__ __launch_bounds__(BLOCK) void pack_pts(
    const float* __restrict__ x1, const float* __restrict__ x2,
    uint4* __restrict__ arrA, uint4* __restrict__ arrB,
    float* __restrict__ wn, unsigned int* __restrict__ mins,
    int n1, int ntot, float* __restrict__ out) {
    int i = blockIdx.x * BLOCK + threadIdx.x;
    if (i == 0) out[0] = 0.0f;
    if (i >= ntot) return;
    const float* s = (i < n1) ? x1 + 3 * (size_t)i : x2 + 3 * (size_t)(i - n1);
    float x = s[0], y = s[1], z = s[2];
    float w = fmaf(z, z, fmaf(y, y, x * x));
    wn[i] = w;
    mins[i] = 0xFFFFFFFFu;  // +inf key
    unsigned int hx = f2bf(x), hy = f2bf(y), hz = f2bf(z);
    unsigned int lx = f2bf(x - bf2f(hx)), ly = f2bf(y - bf2f(hy)), lz = f2bf(z - bf2f(hz));
    unsigned int hw = f2bf(w), lw = f2bf(w - bf2f(hw));
    unsigned int ax = f2bf(-2.f * bf2f(hx)), ay = f2bf(-2.f * bf2f(hy)), az = f2bf(-2.f * bf2f(hz));
    unsigned int bx = f2bf(-2.f * bf2f(lx)), by = f2bf(-2.f * bf2f(ly)), bz = f2bf(-2.f * bf2f(lz));
    const unsigned int one = 0x3F80u;
    arrA[(size_t)i * 2 + 0] = make_uint4(pk2(ax, ay), pk2(az, bx), pk2(by, bz), pk2(ax, ay));
    arrA[(size_t)i * 2 + 1] = make_uint4(pk2(az, one), pk2(one, 0u), 0u, 0u);
    arrB[(size_t)i * 2 + 0] = make_uint4(pk2(hx, hy), pk2(hz, hx), pk2(hy, hz), pk2(lx, ly));
    arrB[(size_t)i * 2 + 1] = make_uint4(pk2(lz, hw), pk2(lw, 0u), 0u, 0u);
}

// MFMA min pass. grid = Bc*2 * SEGS * SCANSPLIT blocks, 4 waves each.
// Each wave owns one 32-row tile (A-frag in regs). Block scans SCANPTS points
// of the other cloud via double-buffered LDS chunks (lo/hi k-half split:
// conflict-free b128 reads). Fold: run[r] = min3(run, acc0, acc1).
// Epilogue: butterfly col-min, order-preserving-key atomicMin per row.
__global__ __launch_bounds__(BLOCK) void chamfer_mfma(
    const uint4* __restrict__ arrA, const uint4* __restrict__ arrB,
    unsigned int* __restrict__ mins, int n1, int Bc) {
    __shared__ uint4 lds[2][2][CHUNK];   // [buf][khalf][pt] : 16KB
    int tid = threadIdx.x;
    int lane = tid & 63, widx = tid >> 6;
    int l31 = lane & 31, blk = lane >> 5;

    int bid = blockIdx.x;
    int sh = bid % SCANSPLIT;
    int t1 = bid / SCANSPLIT;
    int seg = t1 % SEGS;
    int bd = t1 / SEGS;
    int dir = (bd >= Bc) ? 1 : 0;
    int b = dir ? bd - Bc : bd;
    int ownOff = dir ? n1 : 0;
    int othOff = dir ? 0 : n1;

    int row0 = seg * 128 + widx * 32;

    size_t aBase = (size_t)(ownOff + b * NPTS + row0 + l31) * 2 + blk;
    bf16x8 afA = *(const bf16x8*)(arrA + aBase);

    const uint4* gB = arrB + (size_t)(othOff + b * NPTS + sh * SCANPTS) * 2;

    f32x16 run;
#pragma unroll
    for (int r = 0; r < 16; ++r) run[r] = 3.0e38f;

    // stage chunk 0 into buf 0  (t covers 512 uint4: pt = t>>1, khalf = t&1)
    uint4 u0 = gB[tid], u1 = gB[tid + 256];
    lds[0][tid & 1][tid >> 1] = u0;
    lds[0][tid & 1][128 + (tid >> 1)] = u1;
    __syncthreads();

    f32x16 zero = {};
    for (int c = 0; c < NCHUNK; ++c) {
        int cur = c & 1;
        if (c + 1 < NCHUNK) {   // prefetch next chunk into regs
            u0 = gB[(c + 1) * 512 + tid];
            u1 = gB[(c + 1) * 512 + 256 + tid];
        }
        const uint4* lp = lds[cur][blk];
#pragma unroll
        for (int s = 0; s < SUBS; s += 2) {
            bf16x8 bf0 = *(const bf16x8*)(lp + s * 32 + l31);
            bf16x8 bf1 = *(const bf16x8*)(lp + (s + 1) * 32 + l31);
            f32x16 acc0 = __builtin_amdgcn_mfma_f32_32x32x16_bf16(afA, bf0, zero, 0, 0, 0);
            f32x16 acc1 = __builtin_amdgcn_mfma_f32_32x32x16_bf16(afA, bf1, zero, 0, 0, 0);
#pragma unroll
            for (int r = 0; r < 16; ++r)
                run[r] = fminf(run[r], fminf(acc0[r], acc1[r]));  // v_min3_f32
        }
        if (c + 1 < NCHUNK) {
            lds[cur ^ 1][tid & 1][tid >> 1] = u0;
            lds[cur ^ 1][tid & 1][128 + (tid >> 1)] = u1;
        }
        __syncthreads();
    }

    // butterfly min over the 32 columns (within each half-wave)
#pragma unroll
    for (int m = 1; m <= 16; m <<= 1)
#pragma unroll
        for (int r = 0; r < 16; ++r)
            run[r] = fminf(run[r], __shfl_xor(run[r], m, 64));

    // C/D layout: col=lane&31, row=(r&3)+8*(r>>2)+4*(lane>>5)
    if (l31 == 0) {
        unsigned int* mo = mins + ownOff + b * NPTS;
#pragma unroll
        for (int r = 0; r < 16; ++r) {
            int row = row0 + ((r & 3) + 8 * (r >> 2) + 4 * blk);
            atomicMin(mo + row, fkey(run[r]));
        }
    }
}

// Decode keys, add ||p||^2, scale per segment, block-reduce, one atomicAdd.
__global__ __launch_bounds__(BLOCK) void reduce_means(
    const unsigned int* __restrict__ mins, const float* __restrict__ wn,
    int n1, int ntot, float inv1, float inv2, float* __restrict__ out) {
    float s = 0.0f;
    for (int i = blockIdx.x * BLOCK + threadIdx.x; i < ntot; i += gridDim.x * BLOCK) {
        float v = funkey(mins[i]) + wn[i];
        s += v * (i < n1 ? inv1 : inv2);
    }
    for (int off = 32; off; off >>= 1) s += __shfl_down(s, off, 64);
    __shared__ float red[BLOCK / 64];
    int lane = threadIdx.x & 63, wid = threadIdx.x >> 6;
    if (!lane) red[wid] = s;
    __syncthreads();
    if (!threadIdx.x) atomicAdd(out, red[0] + red[1] + red[2] + red[3]);
}

// Fallback (no scratch / unexpected shape): direct-diff scalar path.
__global__ __launch_bounds__(BLOCK) void chamfer_direct(
    const float* __restrict__ x1, const float* __restrict__ x2,
    int Npts, int Mpts, float inv1, float inv2, float* __restrict__ out) {
    int dir = blockIdx.z;
    const float* own = dir ? x2 : x1;
    const float* oth = dir ? x1 : x2;
    int np = dir ? Mpts : Npts;
    int mp = dir ? Npts : Mpts;
    float scale = dir ? inv2 : inv1;

    int bpb = np / BLOCK;
    int b = blockIdx.x / bpb;
    int i = (blockIdx.x % bpb) * BLOCK + threadIdx.x;

    const float* pp = own + ((size_t)b * np + i) * 3;
    float px = pp[0], py = pp[1], pz = pp[2];
    const float* o = oth + (size_t)b * mp * 3;

    float best = 3.0e38f;
#pragma unroll 4
    for (int j = 0; j < mp; ++j) {
        float dx = px - o[3 * j + 0];
        float dy = py - o[3 * j + 1];
        float dz = pz - o[3 * j + 2];
        float d2 = fmaf(dz, dz, fmaf(dy, dy, dx * dx));
        best = fminf(best, d2);
    }
    float s = best * scale;
    for (int off = 32; off; off >>= 1) s += __shfl_down(s, off, 64);
    __shared__ float red[BLOCK / 64];
    int lane = threadIdx.x & 63, wid = threadIdx.x >> 6;
    if (!lane) red[wid] = s;
    __syncthreads();
    if (!threadIdx.x) atomicAdd(out, red[0] + red[1] + red[2] + red[3]);
}

extern "C" void kernel_launch(void* const* d_in, const int* in_sizes, int n_in,
                              void* d_out, int out_size, void* d_ws, size_t ws_size,
                              hipStream_t stream) {
    const float* xyz1 = (const float*)d_in[0];
    const float* xyz2 = (const float*)d_in[1];
    float* out = (float*)d_out;

    const int Bc = in_sizes[0] / (3 * NPTS);
    const int n1 = Bc * NPTS;
    const int n2 = Bc * NPTS;
    const int ntot = n1 + n2;

    size_t need = (size_t)ntot * (32 + 32 + 4 + 4);  // arrA + arrB + wn + mins
    bool okShape = Bc >= 1 && in_sizes[0] == Bc * 3 * NPTS && in_sizes[1] == in_sizes[0];

    if (okShape && ws_size >= need) {
        uint4* arrA = (uint4*)d_ws;
        uint4* arrB = (uint4*)((char*)d_ws + (size_t)ntot * 32);
        float* wn = (float*)((char*)d_ws + (size_t)ntot * 64);
        unsigned int* mins = (unsigned int*)((char*)d_ws + (size_t)ntot * 68);

        pack_pts<<<(ntot + BLOCK - 1) / BLOCK, BLOCK, 0, stream>>>(
            xyz1, xyz2, arrA, arrB, wn, mins, n1, ntot, out);

        chamfer_mfma<<<Bc * 2 * SEGS * SCANSPLIT, BLOCK, 0, stream>>>(
            arrA, arrB, mins, n1, Bc);

        reduce_means<<<64, BLOCK, 0, stream>>>(mins, wn, n1, ntot,
                                               1.0f / (float)n1, 1.0f / (float)n2, out);
    } else {
        hipMemsetAsync(d_out, 0, sizeof(float), stream);
        dim3 grid((in_sizes[0] / 3 / NPTS) * (NPTS / BLOCK), 1, 2);
        chamfer_direct<<<grid, BLOCK, 0, stream>>>(xyz1, xyz2, NPTS, NPTS,
                                                   1.0f / (float)n1, 1.0f / (float)n2, out);
    }
}

// Round 6
// 38.022 us; speedup vs baseline: 1.2233x; 1.0384x over previous
//
#include <hip/hip_runtime.h>

typedef float f32x16 __attribute__((ext_vector_type(16)));
typedef short bf16x8 __attribute__((ext_vector_type(8)));

#define BLOCK 256
#define NPTS 4096
#define SEGS 32                      // 128 rows per block
#define CHUNK 256                    // scanned points per LDS chunk
#define NCHUNK (NPTS / CHUNK)        // 16
#define SUBS (CHUNK / 32)            // 8 col-subtiles per chunk

// ---------- bf16 helpers ----------
__device__ inline unsigned int f2bf(float x) {   // RNE float->bf16 bits
    unsigned int u = __float_as_uint(x);
    return (u + 0x7FFFu + ((u >> 16) & 1)) >> 16;
}
__device__ inline float bf2f(unsigned int b) { return __uint_as_float(b << 16); }
__device__ inline unsigned int pk2(unsigned int lo, unsigned int hi) {
    return (hi << 16) | (lo & 0xFFFFu);
}

// Single fused kernel: packs A-fragments and B-records in-kernel from raw xyz
// (inputs are L2-resident; pack cost amortized), computes q.w - 2*dot via
// verified 32x32x16 bf16 MFMA slot layout:
//   k0..2: -2h * h' ; k3..5: -2l * h' ; k6..8: -2h * l' ; k9: 1*hw' ; k10: 1*lw'
// Each block: 128 rows (4 waves x 32), scans all NPTS points of the other
// cloud via double-buffered conflict-free LDS chunks; completes per-row min
// in-block; adds ||p||^2; one atomicAdd per block. No workspace.
__global__ __launch_bounds__(BLOCK) void chamfer_fused(
    const float* __restrict__ x1, const float* __restrict__ x2,
    int Bc, float inv1, float inv2, float* __restrict__ out) {
    __shared__ uint4 lds[2][2][CHUNK];   // [buf][khalf][pt] : 16KB
    __shared__ float wslot[128];         // ||p||^2 of the block's own rows
    __shared__ float red[4];

    int tid = threadIdx.x;
    int lane = tid & 63, widx = tid >> 6;
    int l31 = lane & 31, blk = lane >> 5;

    int bid = blockIdx.x;
    int seg = bid % SEGS;
    int bd = bid / SEGS;
    int dir = (bd >= Bc) ? 1 : 0;
    int b = dir ? bd - Bc : bd;
    const float* own = dir ? x2 : x1;
    const float* oth = dir ? x1 : x2;
    float inv = dir ? inv2 : inv1;

    int row0 = seg * 128 + widx * 32;    // first row of this wave (within batch)

    // ---- pack own point -> A-fragment (this lane's khalf) ----
    bf16x8 afA;
    {
        const float* p = own + ((size_t)b * NPTS + row0 + l31) * 3;
        float x = p[0], y = p[1], z = p[2];
        float w = fmaf(z, z, fmaf(y, y, x * x));
        unsigned int hx = f2bf(x), hy = f2bf(y), hz = f2bf(z);
        unsigned int lx = f2bf(x - bf2f(hx)), ly = f2bf(y - bf2f(hy)), lz = f2bf(z - bf2f(hz));
        unsigned int ax = f2bf(-2.f * bf2f(hx)), ay = f2bf(-2.f * bf2f(hy)), az = f2bf(-2.f * bf2f(hz));
        unsigned int bx = f2bf(-2.f * bf2f(lx)), by = f2bf(-2.f * bf2f(ly)), bz = f2bf(-2.f * bf2f(lz));
        const unsigned int one = 0x3F80u;
        uint4 A0 = make_uint4(pk2(ax, ay), pk2(az, bx), pk2(by, bz), pk2(ax, ay));
        uint4 A1 = make_uint4(pk2(az, one), pk2(one, 0u), 0u, 0u);
        uint4 af4 = blk ? A1 : A0;
        afA = *(const bf16x8*)&af4;
        if (!blk) wslot[widx * 32 + l31] = w;
    }

    // ---- stage chunk 0 (pack B-record in-kernel) ----
    const float* os = oth + (size_t)b * NPTS * 3;
    {
        const float* q = os + (size_t)tid * 3;
        float x = q[0], y = q[1], z = q[2];
        float w = fmaf(z, z, fmaf(y, y, x * x));
        unsigned int hx = f2bf(x), hy = f2bf(y), hz = f2bf(z);
        unsigned int lx = f2bf(x - bf2f(hx)), ly = f2bf(y - bf2f(hy)), lz = f2bf(z - bf2f(hz));
        unsigned int hw = f2bf(w), lw = f2bf(w - bf2f(hw));
        lds[0][0][tid] = make_uint4(pk2(hx, hy), pk2(hz, hx), pk2(hy, hz), pk2(lx, ly));
        lds[0][1][tid] = make_uint4(pk2(lz, hw), pk2(lw, 0u), 0u, 0u);
    }
    __syncthreads();

    f32x16 run;
#pragma unroll
    for (int r = 0; r < 16; ++r) run[r] = 3.0e38f;

    f32x16 zero = {};
    for (int c = 0; c < NCHUNK; ++c) {
        int cur = c & 1;
        float nx, ny, nz;
        if (c + 1 < NCHUNK) {   // prefetch next chunk's raw xyz
            const float* q = os + (size_t)((c + 1) * CHUNK + tid) * 3;
            nx = q[0]; ny = q[1]; nz = q[2];
        }
        const uint4* lp = lds[cur][blk];
#pragma unroll
        for (int s = 0; s < SUBS; s += 2) {
            bf16x8 bf0 = *(const bf16x8*)(lp + s * 32 + l31);
            bf16x8 bf1 = *(const bf16x8*)(lp + (s + 1) * 32 + l31);
            f32x16 acc0 = __builtin_amdgcn_mfma_f32_32x32x16_bf16(afA, bf0, zero, 0, 0, 0);
            f32x16 acc1 = __builtin_amdgcn_mfma_f32_32x32x16_bf16(afA, bf1, zero, 0, 0, 0);
#pragma unroll
            for (int r = 0; r < 16; ++r)
                run[r] = fminf(run[r], fminf(acc0[r], acc1[r]));  // v_min3_f32
        }
        if (c + 1 < NCHUNK) {
            float w = fmaf(nz, nz, fmaf(ny, ny, nx * nx));
            unsigned int hx = f2bf(nx), hy = f2bf(ny), hz = f2bf(nz);
            unsigned int lx = f2bf(nx - bf2f(hx)), ly = f2bf(ny - bf2f(hy)), lz = f2bf(nz - bf2f(hz));
            unsigned int hw = f2bf(w), lw = f2bf(w - bf2f(hw));
            lds[cur ^ 1][0][tid] = make_uint4(pk2(hx, hy), pk2(hz, hx), pk2(hy, hz), pk2(lx, ly));
            lds[cur ^ 1][1][tid] = make_uint4(pk2(lz, hw), pk2(lw, 0u), 0u, 0u);
        }
        __syncthreads();
    }

    // butterfly min over the 32 columns (within each half-wave)
#pragma unroll
    for (int m = 1; m <= 16; m <<= 1)
#pragma unroll
        for (int r = 0; r < 16; ++r)
            run[r] = fminf(run[r], __shfl_xor(run[r], m, 64));

    // C/D layout: col=lane&31, local row=(r&3)+8*(r>>2)+4*(lane>>5)
    float contrib = 0.0f;
    if (l31 == 0) {
#pragma unroll
        for (int r = 0; r < 16; ++r) {
            int lrow = (r & 3) + 8 * (r >> 2) + 4 * blk;
            contrib += run[r] + wslot[widx * 32 + lrow];
        }
    }
    contrib += __shfl_xor(contrib, 32, 64);
    if (lane == 0) red[widx] = contrib * inv;
    __syncthreads();
    if (tid == 0) atomicAdd(out, red[0] + red[1] + red[2] + red[3]);
}

// Fallback (unexpected shape): direct-diff scalar path, no scratch.
__global__ __launch_bounds__(BLOCK) void chamfer_direct(
    const float* __restrict__ x1, const float* __restrict__ x2,
    int Npts, int Mpts, float inv1, float inv2, float* __restrict__ out) {
    int dir = blockIdx.z;
    const float* own = dir ? x2 : x1;
    const float* oth = dir ? x1 : x2;
    int np = dir ? Mpts : Npts;
    int mp = dir ? Npts : Mpts;
    float scale = dir ? inv2 : inv1;

    int bpb = np / BLOCK;
    int b = blockIdx.x / bpb;
    int i = (blockIdx.x % bpb) * BLOCK + threadIdx.x;

    const float* pp = own + ((size_t)b * np + i) * 3;
    float px = pp[0], py = pp[1], pz = pp[2];
    const float* o = oth + (size_t)b * mp * 3;

    float best = 3.0e38f;
#pragma unroll 4
    for (int j = 0; j < mp; ++j) {
        float dx = px - o[3 * j + 0];
        float dy = py - o[3 * j + 1];
        float dz = pz - o[3 * j + 2];
        float d2 = fmaf(dz, dz, fmaf(dy, dy, dx * dx));
        best = fminf(best, d2);
    }
    float s = best * scale;
    for (int off = 32; off; off >>= 1) s += __shfl_down(s, off, 64);
    __shared__ float red[BLOCK / 64];
    int lane = threadIdx.x & 63, wid = threadIdx.x >> 6;
    if (!lane) red[wid] = s;
    __syncthreads();
    if (!threadIdx.x) atomicAdd(out, red[0] + red[1] + red[2] + red[3]);
}

extern "C" void kernel_launch(void* const* d_in, const int* in_sizes, int n_in,
                              void* d_out, int out_size, void* d_ws, size_t ws_size,
                              hipStream_t stream) {
    const float* xyz1 = (const float*)d_in[0];
    const float* xyz2 = (const float*)d_in[1];
    float* out = (float*)d_out;

    const int Bc = in_sizes[0] / (3 * NPTS);
    const int n1 = Bc * NPTS;
    const int n2 = Bc * NPTS;
    bool okShape = Bc >= 1 && in_sizes[0] == Bc * 3 * NPTS && in_sizes[1] == in_sizes[0];

    hipMemsetAsync(d_out, 0, sizeof(float), stream);

    if (okShape) {
        chamfer_fused<<<Bc * 2 * SEGS, BLOCK, 0, stream>>>(
            xyz1, xyz2, Bc, 1.0f / (float)n1, 1.0f / (float)n2, out);
    } else {
        dim3 grid((in_sizes[0] / 3 / NPTS) * (NPTS / BLOCK), 1, 2);
        chamfer_direct<<<grid, BLOCK, 0, stream>>>(xyz1, xyz2, NPTS, NPTS,
                                                   1.0f / (float)n1, 1.0f / (float)n2, out);
    }
}